// Round 7
// baseline (1771.641 us; speedup 1.0000x reference)
//
#include <hip/hip_runtime.h>

// NearestEmbed (VQ argmin + gather), MI355X gfx950.  Round 10.
// x: (B=64, D=64, H=32, W=32) fp32 ; emb: (D=64, K=512) fp32
// out0: quant (B,D,H,W) fp32 ; out1: argmin (B,H,W) as fp32.
//
// R10 (cross-round synthesis: every tile variant was latency-bound --
// R5 70us with VALU 38us-issue / LDS ~20us / VMEM tiny, nothing saturated,
// 2 waves/SIMD; R6/R8 spilled; R9 exposed global latency at 3 waves/SIMD):
//  * Thread-per-row (lanes = rows) => e operand is WAVE-UNIFORM => scalar
//    path: s_load -> SGPR broadcast in v_fmac. Zero per-lane e traffic.
//    (R3's shape; its failure was x reloaded from GLOBAL when the 64-reg
//    x array didn't fit -- here x comes from a 16KB LDS broadcast read,
//    1 stride-1 ds_read_b32 per 16 FMAs, un-sinkable, never binding.)
//  * Per-thread state = acc[16] + scalars ~ 48 VGPR => 8 waves/SIMD
//    (32/CU, 4x R5's TLP) -- hides s_load/K$ and LDS latency.
//  * 512-thr block = 8 slices x 64 rows; slice scans 64 codes in 4 groups
//    of 16; 1024 blocks. VALU floor ~30us.
//  * Exact chains preserved (d-ascending fmaf for acc and e2; ascending
//    code scan, strict <; slice-ascending merge) -> absmax 0.

constexpr int D    = 64;
constexpr int K    = 512;
constexpr int HW   = 1024;   // 32*32
constexpr int ROWS = 64;     // rows per block (= lanes of a wave)
constexpr int NSL  = 8;      // slices (waves) per block
constexpr int CPS  = K / NSL;  // 64 codes per slice
constexpr int NG   = CPS / 16; // 4 groups of 16

__device__ __forceinline__ void gload16(const float* g, float* l) {
    __builtin_amdgcn_global_load_lds(
        (const __attribute__((address_space(1))) void*)g,
        (__attribute__((address_space(3))) void*)l,
        16, 0, 0);
}

__global__ __launch_bounds__(512, 6) void vq_kernel(
    const float* __restrict__ x,
    const float* __restrict__ emb,
    float* __restrict__ out_q,
    float* __restrict__ out_idx)
{
    __shared__ float xs[D][ROWS];        // 16 KB  xs[d][row]
    __shared__ float e2s[K];             //  2 KB
    __shared__ float mb[NSL - 1][ROWS];  // 1.75 KB
    __shared__ int   mi[NSL - 1][ROWS];  // 1.75 KB
    __shared__ int   kfin[ROWS];         // 256 B   => ~22 KB total

    const int tid   = threadIdx.x;
    const int row   = tid & 63;                                  // lane = row
    const int slice = __builtin_amdgcn_readfirstlane(tid >> 6);  // wave-uniform
    const int r0    = blockIdx.x * ROWS;
    const int b     = r0 >> 10;
    const int n0    = r0 & (HW - 1);

    // ---- stage x tile (64 d x 64 rows) via global_load_lds, once ----
    // dest byte = li*16 (linear = wave-uniform base + lane*16).
    {
        const float* xg = x + ((size_t)b * D) * HW + n0;
        #pragma unroll
        for (int p = 0; p < 2; ++p) {
            const int li = p * 512 + tid;
            const int d  = li >> 4;            // 16 x 16B per 64-float d-row
            const int r4 = (li & 15) << 2;
            gload16(xg + (size_t)d * HW + r4, &xs[d][r4]);
        }
    }

    // ---- ||e_k||^2 : one code per thread (512 = K), coalesced ----
    {
        float s = 0.f;
        #pragma unroll
        for (int d = 0; d < D; ++d) {
            const float v = emb[d * K + tid];
            s = fmaf(v, v, s);
        }
        e2s[tid] = s;
    }
    __syncthreads();   // drains vmcnt (gload16) + flushes e2s

    // ---- scan this slice's 64 codes, 4 groups of 16 ----
    float best = 3.4e38f;
    int   bidx = 0;
    const int kbase = slice * CPS;

    #pragma unroll 1                       // keep code ~9KB (I$-safe)
    for (int g = 0; g < NG; ++g) {
        const int k0 = kbase + g * 16;
        const float* ep = emb + k0;        // wave-uniform -> s_load path
        float acc[16];
        #pragma unroll
        for (int i = 0; i < 16; ++i) acc[i] = 0.f;

        #pragma unroll
        for (int d = 0; d < D; ++d) {
            const float xd = xs[d][row];   // ds_read_b32, stride-1: free
            #pragma unroll
            for (int i = 0; i < 16; ++i)
                acc[i] = fmaf(xd, ep[d * K + i], acc[i]);  // SGPR bcast operand
        }

        #pragma unroll
        for (int i = 0; i < 16; ++i) {
            const float s = fmaf(-2.f, acc[i], e2s[k0 + i]);
            if (s < best) { best = s; bidx = k0 + i; }     // strict <: first idx
        }
    }

    // ---- 8-way slice merge (ascending slice = ascending codes) ----
    if (slice > 0) { mb[slice - 1][row] = best; mi[slice - 1][row] = bidx; }
    __syncthreads();

    if (tid < ROWS) {                      // wave 0 = slice 0 (lowest codes)
        #pragma unroll
        for (int s = 0; s < NSL - 1; ++s) {
            const float ob = mb[s][tid];
            const int   oi = mi[s][tid];
            if (ob < best) { best = ob; bidx = oi; }   // strict <: lower slice wins ties
        }
        kfin[tid] = bidx;
        __builtin_nontemporal_store((float)bidx, &out_idx[r0 + tid]);
    }
    __syncthreads();

    // ---- epilogue: gather emb column, coalesced nontemporal stores ----
    const int dg = tid >> 6;               // 8 threads/row, 8 d-planes each
    const int kq = kfin[row];
    float* oq = out_q + ((size_t)b * D) * HW + n0 + row;
    #pragma unroll
    for (int j = 0; j < 8; ++j) {
        const int d = (dg << 3) + j;
        // emb gather per-lane scattered 4B but L1/L2-hot (128 KB table);
        // stores: consecutive rows across lanes -> full 256B lines.
        __builtin_nontemporal_store(emb[d * K + kq], &oq[(size_t)d * HW]);
    }
}

extern "C" void kernel_launch(void* const* d_in, const int* in_sizes, int n_in,
                              void* d_out, int out_size, void* d_ws, size_t ws_size,
                              hipStream_t stream)
{
    const float* x   = (const float*)d_in[0];   // 4194304 floats
    const float* emb = (const float*)d_in[1];   // 32768 floats

    float* out_q   = (float*)d_out;                     // 4194304 floats
    float* out_idx = out_q + (size_t)64 * 64 * 1024;    // 65536 floats

    // 65536 rows / 64 rows-per-block = 1024 blocks of 512 threads
    // (~22 KB LDS, ~48 VGPR target -> up to 4 blocks/CU = 32 waves/CU)
    vq_kernel<<<1024, 512, 0, stream>>>(x, emb, out_q, out_idx);
}

// Round 8
// 149.673 us; speedup vs baseline: 11.8367x; 11.8367x over previous
//
#include <hip/hip_runtime.h>

// NearestEmbed (VQ argmin + gather), MI355X gfx950.  Round 11.
// x: (B=64, D=64, H=32, W=32) fp32 ; emb: (D=64, K=512) fp32
// out0: quant (B,D,H,W) fp32 ; out1: argmin (B,H,W) as fp32.
//
// R11 (R10 post-mortem: compiler demoted the uniform e-loads to per-lane
// vector loads + spilled acc (VGPR 40, FETCH 1.16GB). R6/R8/R10 all prove
// the scalar-e / reg-x pattern cannot be obtained from C source. Force it:)
//  * e operand: inline-asm s_load_dwordx4 (uniform SGPR base + imm offset)
//    -> SGPR broadcast src in v_fmac. Zero per-lane e traffic, by decree.
//  * x operand: row pinned in 64 VGPRs via 64 inline-asm ds_read_b32 from
//    the LDS x-tile (stride-1 across lanes, conflict-free, one-time).
//    Hot loop = pure v_fmac (no LDS, no VMEM, no addressing).
//  * Bulk depth-0 SMEM per 4-d block + lgkmcnt(0) (SMEM returns are
//    out-of-order -> counted waits unsafe) + sched_barrier(0) (rule #18:
//    compiler hoists reg-only ops past asm waitcnt).  4 waves/SIMD hide it.
//  * Geometry: 1024 blocks x 256 thr; lane=row; 4 slices x 128 codes.
//  * Exact chains preserved (d-ascending fmaf for acc and e2; ascending
//    code scan, strict <; slice-ascending merge) -> absmax 0.

constexpr int D    = 64;
constexpr int K    = 512;
constexpr int HW   = 1024;   // 32*32
constexpr int ROWS = 64;     // rows per block (= lanes of a wave)
constexpr int NSL  = 4;      // slices (waves) per block
constexpr int CPS  = K / NSL;   // 128 codes per slice
constexpr int NG   = CPS / 16;  // 8 groups of 16

typedef float f32x4 __attribute__((ext_vector_type(4)));

__device__ __forceinline__ void gload16(const float* g, float* l) {
    __builtin_amdgcn_global_load_lds(
        (const __attribute__((address_space(1))) void*)g,
        (__attribute__((address_space(3))) void*)l,
        16, 0, 0);
}

__global__ __launch_bounds__(256, 4) void vq_kernel(
    const float* __restrict__ x,
    const float* __restrict__ emb,
    float* __restrict__ out_q,
    float* __restrict__ out_idx)
{
    __shared__ float xs[D][ROWS];        // 16 KB  xs[d][row]
    __shared__ float e2s[K];             //  2 KB
    __shared__ float mb[NSL - 1][ROWS];  // 768 B
    __shared__ int   mi[NSL - 1][ROWS];  // 768 B
    __shared__ int   kfin[ROWS];         // 256 B  => ~20 KB total

    const int tid   = threadIdx.x;
    const int row   = tid & 63;                                  // lane = row
    const int slice = __builtin_amdgcn_readfirstlane(tid >> 6);  // wave id 0..3
    const int r0    = blockIdx.x * ROWS;
    const int b     = r0 >> 10;
    const int n0    = r0 & (HW - 1);

    // ---- stage x tile (64 d x 64 rows) via global_load_lds, once ----
    {
        const float* xg = x + ((size_t)b * D) * HW + n0;
        #pragma unroll
        for (int p = 0; p < 4; ++p) {
            const int li = p * 256 + tid;
            const int d  = li >> 4;            // 16 x 16B per 64-float d-row
            const int r4 = (li & 15) << 2;
            gload16(xg + (size_t)d * HW + r4, &xs[d][r4]);
        }
    }

    // ---- ||e_k||^2 : 2 codes per thread, coalesced (warms L2/K$) ----
    #pragma unroll
    for (int h = 0; h < 2; ++h) {
        const int k = h * 256 + tid;
        float s = 0.f;
        #pragma unroll
        for (int d = 0; d < D; ++d) {
            const float v = emb[d * K + k];
            s = fmaf(v, v, s);
        }
        e2s[k] = s;
    }
    __syncthreads();   // drains vmcnt (gload16) + flushes e2s

    // ---- pin this lane's x row into 64 VGPRs (asm: unsinkable) ----
    // xs[d][row] byte offset = d*256 + row*4; one VGPR addr + imm per d.
    const unsigned xaddr =
        (unsigned)(uintptr_t)(__attribute__((address_space(3))) float*)&xs[0][row];
    float xv[D];
    #pragma unroll
    for (int d = 0; d < D; ++d)
        asm volatile("ds_read_b32 %0, %1 offset:%2"
                     : "=v"(xv[d]) : "v"(xaddr), "i"(d * 256));
    asm volatile("s_waitcnt lgkmcnt(0)" ::: "memory");
    __builtin_amdgcn_sched_barrier(0);

    float best = 3.4e38f;
    int   bidx = 0;

    #pragma unroll 1                       // bound code size (body ~11KB)
    for (int g = 0; g < NG; ++g) {
        const int k0 = slice * CPS + g * 16;
        const float* ep = emb + k0;        // wave-uniform -> SGPR pair
        float acc[16];
        #pragma unroll
        for (int i = 0; i < 16; ++i) acc[i] = 0.f;

        #pragma unroll
        for (int db = 0; db < 16; ++db) {  // 16 blocks of 4 d
            f32x4 e[16];                   // [q*4+j]: d=4db+q, codes 4j..4j+3
            #pragma unroll
            for (int q = 0; q < 4; ++q)
                #pragma unroll
                for (int j = 0; j < 4; ++j)
                    asm volatile("s_load_dwordx4 %0, %1, %2"
                                 : "=s"(e[q * 4 + j])
                                 : "s"(ep), "i"((4 * db + q) * 2048 + j * 16));
            asm volatile("s_waitcnt lgkmcnt(0)" ::: "memory");
            __builtin_amdgcn_sched_barrier(0);

            #pragma unroll
            for (int q = 0; q < 4; ++q) {          // d ascending (4db+q)
                const float xd = xv[4 * db + q];
                #pragma unroll
                for (int j = 0; j < 4; ++j) {
                    acc[j * 4 + 0] = fmaf(xd, e[q * 4 + j][0], acc[j * 4 + 0]);
                    acc[j * 4 + 1] = fmaf(xd, e[q * 4 + j][1], acc[j * 4 + 1]);
                    acc[j * 4 + 2] = fmaf(xd, e[q * 4 + j][2], acc[j * 4 + 2]);
                    acc[j * 4 + 3] = fmaf(xd, e[q * 4 + j][3], acc[j * 4 + 3]);
                }
            }
        }

        // scoring: s = e2 - 2*acc (identical fp32 chain); ascending i,
        // strict < => first index; groups/slices ascend.
        #pragma unroll
        for (int i = 0; i < 16; ++i) {
            const float s = fmaf(-2.f, acc[i], e2s[k0 + i]);
            if (s < best) { best = s; bidx = k0 + i; }
        }
    }

    // ---- 4-way slice merge (ascending slice = ascending codes) ----
    if (slice > 0) { mb[slice - 1][row] = best; mi[slice - 1][row] = bidx; }
    __syncthreads();

    if (tid < ROWS) {                      // wave 0 = slice 0 (lowest codes)
        #pragma unroll
        for (int s = 0; s < NSL - 1; ++s) {
            const float ob = mb[s][tid];
            const int   oi = mi[s][tid];
            if (ob < best) { best = ob; bidx = oi; }  // strict <: lower slice wins
        }
        kfin[tid] = bidx;
        __builtin_nontemporal_store((float)bidx, &out_idx[r0 + tid]);
    }
    __syncthreads();

    // ---- epilogue: gather emb column, coalesced nontemporal stores ----
    const int dg = tid >> 6;               // 4 threads/row, 16 d-planes each
    const int kq = kfin[row];
    float* oq = out_q + ((size_t)b * D) * HW + n0 + row;
    #pragma unroll
    for (int j = 0; j < 16; ++j) {
        const int d = (dg << 4) + j;
        // emb gather per-lane scattered 4B but L1/L2-hot (128 KB table);
        // stores: consecutive rows across lanes -> full 256B lines.
        __builtin_nontemporal_store(emb[d * K + kq], &oq[(size_t)d * HW]);
    }
}

extern "C" void kernel_launch(void* const* d_in, const int* in_sizes, int n_in,
                              void* d_out, int out_size, void* d_ws, size_t ws_size,
                              hipStream_t stream)
{
    const float* x   = (const float*)d_in[0];   // 4194304 floats
    const float* emb = (const float*)d_in[1];   // 32768 floats

    float* out_q   = (float*)d_out;                     // 4194304 floats
    float* out_idx = out_q + (size_t)64 * 64 * 1024;    // 65536 floats

    // 65536 rows / 64 rows-per-block = 1024 blocks of 256 threads
    // (~20 KB LDS, ~96 VGPR -> 4 blocks/CU, 16 waves/CU, 4 waves/SIMD)
    vq_kernel<<<1024, 256, 0, stream>>>(x, emb, out_q, out_idx);
}

// Round 9
// 148.803 us; speedup vs baseline: 11.9060x; 1.0058x over previous
//
#include <hip/hip_runtime.h>

// NearestEmbed (VQ argmin + gather), MI355X gfx950.  Round 12.
// x: (B=64, D=64, H=32, W=32) fp32 ; emb: (D=64, K=512) fp32
// out0: quant (B,D,H,W) fp32 ; out1: argmin (B,H,W) as fp32.
//
// R12 = R11 + __attribute__((amdgpu_waves_per_eu(4,4))).
// R11 post-mortem: memory side finally clean (WRITE=outputs only), but
// VGPR_Count=60 -> xv[64] spilled to (L2-absorbed) scratch. Cross-round
// pattern (R8:64, R9:60, R10:40, R11:60) shows hipcc's launch_bounds sets
// only the MIN of amdgpu-waves-per-eu; the backend chases the max (8/EU),
// capping VGPRs at ~64 and spilling. Pinning waves-per-eu to exactly 4
// raises the cap to 128 and forbids the occupancy-chasing spill.
//  * e operand: inline-asm s_load_dwordx4 (uniform base + imm) -> SGPR
//    broadcast src in v_fmac. Zero per-lane e traffic.
//  * x operand: row pinned in 64 VGPRs via one-time asm ds_read_b32
//    (stride-1 across lanes, conflict-free). Hot loop = pure v_fmac.
//  * Bulk SMEM drain per 4-d block (lgkmcnt(0) + sched_barrier, rule #18);
//    4 waves/SIMD hide the K$ latency (512 cy FMA issue vs ~200 cy drain).
//  * Exact chains preserved (d-ascending fmaf for acc and e2; ascending
//    code scan, strict <; slice-ascending merge) -> absmax 0.

constexpr int D    = 64;
constexpr int K    = 512;
constexpr int HW   = 1024;   // 32*32
constexpr int ROWS = 64;     // rows per block (= lanes of a wave)
constexpr int NSL  = 4;      // slices (waves) per block
constexpr int CPS  = K / NSL;   // 128 codes per slice
constexpr int NG   = CPS / 16;  // 8 groups of 16

typedef float f32x4 __attribute__((ext_vector_type(4)));

__device__ __forceinline__ void gload16(const float* g, float* l) {
    __builtin_amdgcn_global_load_lds(
        (const __attribute__((address_space(1))) void*)g,
        (__attribute__((address_space(3))) void*)l,
        16, 0, 0);
}

__global__ __launch_bounds__(256)
__attribute__((amdgpu_waves_per_eu(4, 4)))
void vq_kernel(
    const float* __restrict__ x,
    const float* __restrict__ emb,
    float* __restrict__ out_q,
    float* __restrict__ out_idx)
{
    __shared__ float xs[D][ROWS];        // 16 KB  xs[d][row]
    __shared__ float e2s[K];             //  2 KB
    __shared__ float mb[NSL - 1][ROWS];  // 768 B
    __shared__ int   mi[NSL - 1][ROWS];  // 768 B
    __shared__ int   kfin[ROWS];         // 256 B  => ~20 KB total

    const int tid   = threadIdx.x;
    const int row   = tid & 63;                                  // lane = row
    const int slice = __builtin_amdgcn_readfirstlane(tid >> 6);  // wave id 0..3
    const int r0    = blockIdx.x * ROWS;
    const int b     = r0 >> 10;
    const int n0    = r0 & (HW - 1);

    // ---- stage x tile (64 d x 64 rows) via global_load_lds, once ----
    {
        const float* xg = x + ((size_t)b * D) * HW + n0;
        #pragma unroll
        for (int p = 0; p < 4; ++p) {
            const int li = p * 256 + tid;
            const int d  = li >> 4;            // 16 x 16B per 64-float d-row
            const int r4 = (li & 15) << 2;
            gload16(xg + (size_t)d * HW + r4, &xs[d][r4]);
        }
    }

    // ---- ||e_k||^2 : 2 codes per thread, coalesced (warms L2/K$) ----
    #pragma unroll
    for (int h = 0; h < 2; ++h) {
        const int k = h * 256 + tid;
        float s = 0.f;
        #pragma unroll
        for (int d = 0; d < D; ++d) {
            const float v = emb[d * K + k];
            s = fmaf(v, v, s);
        }
        e2s[k] = s;
    }
    __syncthreads();   // drains vmcnt (gload16) + flushes e2s

    // ---- pin this lane's x row into 64 VGPRs (asm: unsinkable) ----
    // xs[d][row] byte offset = d*256 + row*4; one VGPR addr + imm per d.
    const unsigned xaddr =
        (unsigned)(uintptr_t)(__attribute__((address_space(3))) float*)&xs[0][row];
    float xv[D];
    #pragma unroll
    for (int d = 0; d < D; ++d)
        asm volatile("ds_read_b32 %0, %1 offset:%2"
                     : "=v"(xv[d]) : "v"(xaddr), "i"(d * 256));
    asm volatile("s_waitcnt lgkmcnt(0)" ::: "memory");
    __builtin_amdgcn_sched_barrier(0);

    float best = 3.4e38f;
    int   bidx = 0;

    #pragma unroll 1                       // bound code size (body ~11KB)
    for (int g = 0; g < NG; ++g) {
        const int k0 = slice * CPS + g * 16;
        const float* ep = emb + k0;        // wave-uniform -> SGPR pair
        float acc[16];
        #pragma unroll
        for (int i = 0; i < 16; ++i) acc[i] = 0.f;

        #pragma unroll
        for (int db = 0; db < 16; ++db) {  // 16 blocks of 4 d
            f32x4 e[16];                   // [q*4+j]: d=4db+q, codes 4j..4j+3
            #pragma unroll
            for (int q = 0; q < 4; ++q)
                #pragma unroll
                for (int j = 0; j < 4; ++j)
                    asm volatile("s_load_dwordx4 %0, %1, %2"
                                 : "=s"(e[q * 4 + j])
                                 : "s"(ep), "i"((4 * db + q) * 2048 + j * 16));
            asm volatile("s_waitcnt lgkmcnt(0)" ::: "memory");
            __builtin_amdgcn_sched_barrier(0);

            #pragma unroll
            for (int q = 0; q < 4; ++q) {          // d ascending (4db+q)
                const float xd = xv[4 * db + q];
                #pragma unroll
                for (int j = 0; j < 4; ++j) {
                    acc[j * 4 + 0] = fmaf(xd, e[q * 4 + j][0], acc[j * 4 + 0]);
                    acc[j * 4 + 1] = fmaf(xd, e[q * 4 + j][1], acc[j * 4 + 1]);
                    acc[j * 4 + 2] = fmaf(xd, e[q * 4 + j][2], acc[j * 4 + 2]);
                    acc[j * 4 + 3] = fmaf(xd, e[q * 4 + j][3], acc[j * 4 + 3]);
                }
            }
        }

        // scoring: s = e2 - 2*acc (identical fp32 chain); ascending i,
        // strict < => first index; groups/slices ascend.
        #pragma unroll
        for (int i = 0; i < 16; ++i) {
            const float s = fmaf(-2.f, acc[i], e2s[k0 + i]);
            if (s < best) { best = s; bidx = k0 + i; }
        }
    }

    // ---- 4-way slice merge (ascending slice = ascending codes) ----
    if (slice > 0) { mb[slice - 1][row] = best; mi[slice - 1][row] = bidx; }
    __syncthreads();

    if (tid < ROWS) {                      // wave 0 = slice 0 (lowest codes)
        #pragma unroll
        for (int s = 0; s < NSL - 1; ++s) {
            const float ob = mb[s][tid];
            const int   oi = mi[s][tid];
            if (ob < best) { best = ob; bidx = oi; }  // strict <: lower slice wins
        }
        kfin[tid] = bidx;
        __builtin_nontemporal_store((float)bidx, &out_idx[r0 + tid]);
    }
    __syncthreads();

    // ---- epilogue: gather emb column, coalesced nontemporal stores ----
    const int dg = tid >> 6;               // 4 threads/row, 16 d-planes each
    const int kq = kfin[row];
    float* oq = out_q + ((size_t)b * D) * HW + n0 + row;
    #pragma unroll
    for (int j = 0; j < 16; ++j) {
        const int d = (dg << 4) + j;
        // emb gather per-lane scattered 4B but L1/L2-hot (128 KB table);
        // stores: consecutive rows across lanes -> full 256B lines.
        __builtin_nontemporal_store(emb[d * K + kq], &oq[(size_t)d * HW]);
    }
}

extern "C" void kernel_launch(void* const* d_in, const int* in_sizes, int n_in,
                              void* d_out, int out_size, void* d_ws, size_t ws_size,
                              hipStream_t stream)
{
    const float* x   = (const float*)d_in[0];   // 4194304 floats
    const float* emb = (const float*)d_in[1];   // 32768 floats

    float* out_q   = (float*)d_out;                     // 4194304 floats
    float* out_idx = out_q + (size_t)64 * 64 * 1024;    // 65536 floats

    // 65536 rows / 64 rows-per-block = 1024 blocks of 256 threads
    // (~20 KB LDS, target ~96 VGPR @ waves_per_eu(4,4) -> 16 waves/CU)
    vq_kernel<<<1024, 256, 0, stream>>>(x, emb, out_q, out_idx);
}